// Round 2
// baseline (160.048 us; speedup 1.0000x reference)
//
#include <hip/hip_runtime.h>
#include <hip/hip_bf16.h>
#include <math.h>

#define NB 2
#define NS 2048
#define ND 768
#define NH 12
#define HD 64
#define WIN 128
#define N_QKV 2304
#define QKN (NB * NH * NS * HD)   // 3145728

typedef __attribute__((ext_vector_type(8))) short short8;
typedef __attribute__((ext_vector_type(4))) short short4v;
typedef __attribute__((ext_vector_type(4))) float float4v;

static __device__ __forceinline__ short f2bf(float f) {
  __hip_bfloat16 h = __float2bfloat16(f);
  short s;
  __builtin_memcpy(&s, &h, 2);
  return s;
}

// K=16 bf16 MFMA: B-operand layout k = 4*g + e matches the S^T C-layout
// (lane g holds keys 4g+r) -> shuffle-free PV.
static __device__ __forceinline__ float4v mfma_16x16x16_bf16(short4v a, short4v b, float4v c) {
#if __has_builtin(__builtin_amdgcn_mfma_f32_16x16x16bf16_1k)
  return __builtin_amdgcn_mfma_f32_16x16x16bf16_1k(a, b, c, 0, 0, 0);
#else
  float4v d;
  asm("v_mfma_f32_16x16x16_bf16 %0, %1, %2, %3"
      : "=v"(d) : "v"(a), "v"(b), "v"(c));
  return d;
#endif
}

static __device__ __forceinline__ void async_copy16(void* lds, const void* g) {
  __builtin_amdgcn_global_load_lds(
      (const __attribute__((address_space(1))) unsigned int*)g,
      (__attribute__((address_space(3))) unsigned int*)(unsigned int)(unsigned long long)lds,
      16, 0, 0);
}

// ---------------------------------------------------------------------------
// Merged prep kernel: x cvt (3072 units) + Wqkv^T (1728) + Wout^T (576).
// ---------------------------------------------------------------------------
__global__ __launch_bounds__(256) void prep_kernel(
    const float* __restrict__ x, const float* __restrict__ Wqkv,
    const float* __restrict__ Wout, short* __restrict__ xb,
    short* __restrict__ Wqkvt, short* __restrict__ Woutt)
{
  __shared__ float t[32][33];
  const int u = blockIdx.x;
  const int tid = threadIdx.x;

  if (u < 3072) {
    const int i = u * 1024 + tid * 4;
    const float4 v = *(const float4*)(x + i);
    short4v o;
    o[0] = f2bf(v.x); o[1] = f2bf(v.y); o[2] = f2bf(v.z); o[3] = f2bf(v.w);
    *(short4v*)(xb + i) = o;
    return;
  }

  const bool isqkv = (u < 4800);
  const float* in = isqkv ? Wqkv : Wout;
  short* out = isqkv ? Wqkvt : Woutt;
  const int C = isqkv ? N_QKV : ND;       // in cols
  const int tt = u - (isqkv ? 3072 : 4800);
  const int nbx = C / 32;
  const int bx = (tt % nbx) * 32;         // col base
  const int by = (tt / nbx) * 32;         // row base
  const int tx = tid & 31, ty = tid >> 5; // ty 0..7
#pragma unroll
  for (int i = 0; i < 32; i += 8)
    t[ty + i][tx] = in[(size_t)(by + ty + i) * C + bx + tx];
  __syncthreads();
#pragma unroll
  for (int i = 0; i < 32; i += 8)
    out[(size_t)(bx + ty + i) * ND + by + tx] = f2bf(t[tx][ty + i]);
}

// ---------------------------------------------------------------------------
// MFMA GEMM: 128x64 tile, BK=64, 4 waves each 32x64 via 2x4 16x16x32 bf16
// frags, global_load_lds width-16 staging, XOR-swizzled K-chunk LDS slots.
// (R1 post-mortem: 128x128 regressed at K=768 — low grid (2.25/CU) can't
// hide the sincos-heavy epilogue; reverted to the verified 128x64 form.)
// MODE 0: qkv epilogue (bias + RoPE -> Qb/Kb [bh][s][64], V -> VT
//         [bh][64][s]).  MODE 1: plain fp32 out = acc + bias.
// ---------------------------------------------------------------------------
template <int MODE>
__global__ __launch_bounds__(256) void mfma_gemm128_kernel(
    const short* __restrict__ A, const short* __restrict__ Bt,
    const float* __restrict__ bias, const int* __restrict__ layer_idx_p,
    short* __restrict__ Qb, short* __restrict__ Kb, short* __restrict__ VT,
    float* __restrict__ Out, int K, int Ncols, int nTN, int mPerXcd)
{
  __shared__ short As[128 * 64];   // 16 KB
  __shared__ short Bs[64 * 64];    //  8 KB
  const int tid = threadIdx.x;
  const int w = tid >> 6, lane = tid & 63;
  const int c = lane & 15, g = lane >> 4;

  // XCD-aware swizzle: xcd = id&7 owns m-tiles [xcd*mPerXcd, ...+mPerXcd)
  const int id = blockIdx.x;
  const int xcd = id & 7;
  const int k = id >> 3;
  const int mt = xcd * mPerXcd + k / nTN;
  const int nt = k - (k / nTN) * nTN;
  const int bm = mt * 128, bn = nt * 64;

  const int lr = lane >> 3;            // staging row 0..7
  const int gch = (lane & 7) ^ lr;     // swizzled global K-chunk index

  float4v acc[2][4];
#pragma unroll
  for (int i = 0; i < 2; ++i)
#pragma unroll
    for (int j = 0; j < 4; ++j) acc[i][j] = (float4v){0.f, 0.f, 0.f, 0.f};

  const short* Ag = A + (size_t)(bm + w * 32 + lr) * K + gch * 8;
  const short* Bg = Bt + (size_t)(bn + w * 16 + lr) * K + gch * 8;
  short* AsW = As + (w * 32) * 64;     // wave-uniform LDS stage base
  short* BsW = Bs + (w * 16) * 64;

  const int cl7 = c & 7;
  const short* aw = As + (w * 32 + c) * 64;
  const short* bwp = Bs + c * 64;

  for (int k0 = 0; k0 < K; k0 += 64) {
    async_copy16(AsW,        Ag + k0);
    async_copy16(AsW + 512,  Ag + k0 + (size_t)8 * K);
    async_copy16(AsW + 1024, Ag + k0 + (size_t)16 * K);
    async_copy16(AsW + 1536, Ag + k0 + (size_t)24 * K);
    async_copy16(BsW,        Bg + k0);
    async_copy16(BsW + 512,  Bg + k0 + (size_t)8 * K);
    __syncthreads();   // drains vmcnt -> staged data visible

    short8 af[2][2], bfr[4][2];
#pragma unroll
    for (int t = 0; t < 2; ++t) {
      const int slot = ((t * 4 + g) ^ cl7) * 8;
#pragma unroll
      for (int i = 0; i < 2; ++i) af[i][t] = *(const short8*)(aw + i * 16 * 64 + slot);
#pragma unroll
      for (int j = 0; j < 4; ++j) bfr[j][t] = *(const short8*)(bwp + j * 16 * 64 + slot);
    }
#pragma unroll
    for (int t = 0; t < 2; ++t)
#pragma unroll
      for (int i = 0; i < 2; ++i)
#pragma unroll
        for (int j = 0; j < 4; ++j)
          acc[i][j] = __builtin_amdgcn_mfma_f32_16x16x32_bf16(af[i][t], bfr[j][t], acc[i][j], 0, 0, 0);
    __syncthreads();   // protect LDS before next stage
  }

  const int wm = bm + w * 32;
  const int wn = bn;
  float bj[4];
#pragma unroll
  for (int j = 0; j < 4; ++j) bj[j] = bias[wn + j * 16 + c];

  if (MODE == 1) {
#pragma unroll
    for (int i = 0; i < 2; ++i)
#pragma unroll
      for (int j = 0; j < 4; ++j)
#pragma unroll
        for (int r = 0; r < 4; ++r)
          Out[(size_t)(wm + i * 16 + 4 * g + r) * Ncols + wn + j * 16 + c] =
              acc[i][j][r] + bj[j];
  } else {
    const int which = bn / ND;               // uniform per block (768%64==0)
    const int hd0 = wn - which * ND;         // 64-aligned
    const int h = hd0 >> 6;
    const int bidx = bm >> 11;
    const int srow = (bm & (NS - 1)) + w * 32;

    if (which == 2) {
      // V: no RoPE; VT[bh][d][s], short4 along s
#pragma unroll
      for (int j = 0; j < 4; ++j) {
        const int d = j * 16 + c;
        short* vbase = VT + ((size_t)(bidx * NH + h) * HD + d) * NS;
#pragma unroll
        for (int i = 0; i < 2; ++i) {
          short4v v4;
#pragma unroll
          for (int r = 0; r < 4; ++r) v4[r] = f2bf(acc[i][j][r] + bj[j]);
          *(short4v*)(vbase + srow + i * 16 + 4 * g) = v4;
        }
      }
    } else {
      const bool is_global = ((*layer_idx_p) % 3) == 0;
      const float theta = is_global ? 160000.0f : 10000.0f;
      const float nlt = -__logf(theta) * (1.0f / 64.0f);
      short* dst = which ? Kb : Qb;
      const bool oddc = (c & 1);
#pragma unroll
      for (int j = 0; j < 4; ++j) {
        const int d = j * 16 + c;
        const float freq = __expf((float)(d & ~1) * nlt);
#pragma unroll
        for (int i = 0; i < 2; ++i) {
#pragma unroll
          for (int r = 0; r < 4; ++r) {
            const float val = acc[i][j][r] + bj[j];
            const float partner = __shfl_xor(val, 1);
            const int s = srow + i * 16 + 4 * g + r;
            float sn, cs;
            __sincosf((float)s * freq, &sn, &cs);
            const float o = oddc ? (val * cs + partner * sn)
                                 : (val * cs - partner * sn);
            dst[((size_t)(bidx * NH + h) * NS + s) * HD + d] = f2bf(o);
          }
        }
      }
    }
  }
}

// ---------------------------------------------------------------------------
// MFMA banded flash attention (fixed-reference softmax). XCD-aware swizzle
// — each XCD owns 3 heads (K+V slab 1.5 MB -> L2-resident).
// R2: shuffle-free PV. The S^T fragment (lane g holds keys 4g+r) feeds
// v_mfma_f32_16x16x16_bf16's B-operand (k = 4g+e) DIRECTLY, so the
// 16 ds_bpermute per tile are gone; PV = 8 K=16 MFMAs (2 per d-quadrant).
// ---------------------------------------------------------------------------
__global__ __launch_bounds__(256) void attn_mfma_kernel(
    const short* __restrict__ Qb, const short* __restrict__ Kb,
    const short* __restrict__ VT, short* __restrict__ CTXb,
    const int* __restrict__ layer_idx_p)
{
  const int lane = threadIdx.x & 63;
  const int wv = threadIdx.x >> 6;
  const int c = lane & 15;
  const int g = lane >> 4;

  // swizzle: xcd = id&7 owns bh in [xcd*3, xcd*3+3)
  const int id = blockIdx.x;
  const int xcd = id & 7;
  const int k = id >> 3;               // 0..95
  const int bh = xcd * 3 + (k >> 5);
  const int qt = k & 31;

  const int b = bh / NH;
  const int h = bh - b * NH;
  const int q0 = qt * 64 + wv * 16;
  const bool is_global = ((*layer_idx_p) % 3) == 0;
  const size_t base = (size_t)bh * NS * HD;

  const short* qrow = Qb + base + (size_t)(q0 + c) * HD + g * 8;
  const short8 qf0 = *(const short8*)(qrow);
  const short8 qf1 = *(const short8*)(qrow + 32);

  float4v O0 = {0.f, 0.f, 0.f, 0.f}, O1 = O0, O2 = O0, O3 = O0;
  float lacc = 0.0f;
  const int q = q0 + c;

  const int lo = is_global ? 0 : q0 - 128;
  const int hi = is_global ? (NS - 1) : q0 + 143;

  for (int kt = lo; kt <= hi; kt += 32) {
    if (kt + 31 < 0 || kt >= NS) continue;

    const int k1c = min(max(kt + c, 0), NS - 1);
    const int k2c = min(max(kt + 16 + c, 0), NS - 1);
    const short* kr1 = Kb + base + (size_t)k1c * HD + g * 8;
    const short* kr2 = Kb + base + (size_t)k2c * HD + g * 8;
    const short8 kf10 = *(const short8*)kr1;
    const short8 kf11 = *(const short8*)(kr1 + 32);
    const short8 kf20 = *(const short8*)kr2;
    const short8 kf21 = *(const short8*)(kr2 + 32);
    float4v st1 = {0.f, 0.f, 0.f, 0.f}, st2 = {0.f, 0.f, 0.f, 0.f};
    st1 = __builtin_amdgcn_mfma_f32_16x16x32_bf16(kf10, qf0, st1, 0, 0, 0);
    st1 = __builtin_amdgcn_mfma_f32_16x16x32_bf16(kf11, qf1, st1, 0, 0, 0);
    st2 = __builtin_amdgcn_mfma_f32_16x16x32_bf16(kf20, qf0, st2, 0, 0, 0);
    st2 = __builtin_amdgcn_mfma_f32_16x16x32_bf16(kf21, qf1, st2, 0, 0, 0);

    float p1[4], p2[4];
#pragma unroll
    for (int r = 0; r < 4; ++r) {
      const int key1 = kt + 4 * g + r;
      const int key2 = key1 + 16;
      const bool v1 = (key1 >= 0) & (key1 < NS) &
                      (is_global | ((key1 - q <= WIN) & (q - key1 <= WIN)));
      const bool v2 = (key2 >= 0) & (key2 < NS) &
                      (is_global | ((key2 - q <= WIN) & (q - key2 <= WIN)));
      p1[r] = __expf(v1 ? st1[r] * 0.125f : -1e30f);
      p2[r] = __expf(v2 ? st2[r] * 0.125f : -1e30f);
      lacc += p1[r] + p2[r];
    }

    // P -> bf16 B-frags for K=16 MFMA: zero cross-lane movement.
    short4v pf1, pf2;
#pragma unroll
    for (int r = 0; r < 4; ++r) {
      pf1[r] = f2bf(p1[r]);
      pf2[r] = f2bf(p2[r]);
    }

    // V A-frags: A[m=d(=c)][k=4g+e] -> VT[d][kt(+16)+4g ..+3], 8B loads.
    const int ksa = min(max(kt + 4 * g, 0), NS - 4);
    const int ksb = min(max(kt + 16 + 4 * g, 0), NS - 4);
    const short* vcol = VT + base + (size_t)c * NS;
    const short4v va0 = *(const short4v*)(vcol + ksa);
    const short4v vb0 = *(const short4v*)(vcol + ksb);
    const short4v va1 = *(const short4v*)(vcol + 16 * NS + ksa);
    const short4v vb1 = *(const short4v*)(vcol + 16 * NS + ksb);
    const short4v va2 = *(const short4v*)(vcol + 32 * NS + ksa);
    const short4v vb2 = *(const short4v*)(vcol + 32 * NS + ksb);
    const short4v va3 = *(const short4v*)(vcol + 48 * NS + ksa);
    const short4v vb3 = *(const short4v*)(vcol + 48 * NS + ksb);

    O0 = mfma_16x16x16_bf16(va0, pf1, O0);
    O1 = mfma_16x16x16_bf16(va1, pf1, O1);
    O2 = mfma_16x16x16_bf16(va2, pf1, O2);
    O3 = mfma_16x16x16_bf16(va3, pf1, O3);
    O0 = mfma_16x16x16_bf16(vb0, pf2, O0);
    O1 = mfma_16x16x16_bf16(vb1, pf2, O1);
    O2 = mfma_16x16x16_bf16(vb2, pf2, O2);
    O3 = mfma_16x16x16_bf16(vb3, pf2, O3);
  }

  // epilogue: one cross-quad reduction of l, then scale+store (short4)
  lacc += __shfl_xor(lacc, 16);
  lacc += __shfl_xor(lacc, 32);
  const float inv = 1.0f / lacc;
  short* crow = CTXb + ((size_t)(b * NS + q) * NH + h) * HD;
  short4v s0, s1, s2, s3;
#pragma unroll
  for (int r = 0; r < 4; ++r) {
    s0[r] = f2bf(O0[r] * inv);
    s1[r] = f2bf(O1[r] * inv);
    s2[r] = f2bf(O2[r] * inv);
    s3[r] = f2bf(O3[r] * inv);
  }
  *(short4v*)(crow + 4 * g)      = s0;
  *(short4v*)(crow + 16 + 4 * g) = s1;
  *(short4v*)(crow + 32 + 4 * g) = s2;
  *(short4v*)(crow + 48 + 4 * g) = s3;
}

// ---------------------------------------------------------------------------
extern "C" void kernel_launch(void* const* d_in, const int* in_sizes, int n_in,
                              void* d_out, int out_size, void* d_ws, size_t ws_size,
                              hipStream_t stream) {
  const float* x    = (const float*)d_in[0];
  const float* Wqkv = (const float*)d_in[1];
  const float* bqkv = (const float*)d_in[2];
  const float* Wout = (const float*)d_in[3];
  const float* bout = (const float*)d_in[4];
  const int* layer_idx = (const int*)d_in[5];

  short* xb    = (short*)d_ws;                         // [4096][768]
  short* Wqkvt = xb + (size_t)NB * NS * ND;            // [2304][768]
  short* Woutt = Wqkvt + (size_t)ND * N_QKV;           // [768][768]
  short* Qb    = Woutt + (size_t)ND * ND;              // [bh][s][64]
  short* Kb    = Qb + (size_t)QKN;
  short* VT    = Kb + (size_t)QKN;                     // [bh][64][s]
  short* CTXb  = VT + (size_t)QKN;                     // [4096][768]
  // total: 18087936 shorts = 36.2 MB

  // phase 0: all preps in one dispatch
  prep_kernel<<<5376, 256, 0, stream>>>(x, Wqkv, Wout, xb, Wqkvt, Woutt);

  // QKV GEMM + RoPE: M=4096, N=2304, K=768. 32 m-tiles x 36 n-tiles = 1152.
  mfma_gemm128_kernel<0><<<1152, 256, 0, stream>>>(
      xb, Wqkvt, bqkv, layer_idx, Qb, Kb, VT, nullptr, ND, N_QKV, 36, 4);

  attn_mfma_kernel<<<NB * NH * (NS / 64), 256, 0, stream>>>(Qb, Kb, VT, CTXb, layer_idx);

  // Out projection: M=4096, N=768, K=768. 32 m-tiles x 12 n-tiles = 384.
  mfma_gemm128_kernel<1><<<384, 256, 0, stream>>>(
      CTXb, Woutt, bout, layer_idx, nullptr, nullptr, nullptr, (float*)d_out, ND, ND, 12, 4);
}

// Round 3
// 150.585 us; speedup vs baseline: 1.0628x; 1.0628x over previous
//
#include <hip/hip_runtime.h>
#include <hip/hip_bf16.h>
#include <math.h>

#define NB 2
#define NS 2048
#define ND 768
#define NH 12
#define HD 64
#define WIN 128
#define N_QKV 2304
#define QKN (NB * NH * NS * HD)   // 3145728

typedef __attribute__((ext_vector_type(8))) short short8;
typedef __attribute__((ext_vector_type(4))) short short4v;
typedef __attribute__((ext_vector_type(4))) float float4v;

static __device__ __forceinline__ short f2bf(float f) {
  __hip_bfloat16 h = __float2bfloat16(f);
  short s;
  __builtin_memcpy(&s, &h, 2);
  return s;
}

static __device__ __forceinline__ void async_copy16(void* lds, const void* g) {
  __builtin_amdgcn_global_load_lds(
      (const __attribute__((address_space(1))) unsigned int*)g,
      (__attribute__((address_space(3))) unsigned int*)(unsigned int)(unsigned long long)lds,
      16, 0, 0);
}

// ---------------------------------------------------------------------------
// Merged prep kernel: x cvt (3072) + Wqkv^T (1728) + Wout^T (576) +
// R3: RoPE cos/sin table (256 blocks): tab[s][dp] = {cos,sin}(s * freq(2dp)),
// computed with the SAME float expressions as the old epilogue (bit-identical).
// ---------------------------------------------------------------------------
__global__ __launch_bounds__(256) void prep_kernel(
    const float* __restrict__ x, const float* __restrict__ Wqkv,
    const float* __restrict__ Wout, const int* __restrict__ layer_idx_p,
    short* __restrict__ xb, short* __restrict__ Wqkvt,
    short* __restrict__ Woutt, float* __restrict__ tab)
{
  __shared__ float t[32][33];
  const int u = blockIdx.x;
  const int tid = threadIdx.x;

  if (u < 3072) {
    const int i = u * 1024 + tid * 4;
    const float4 v = *(const float4*)(x + i);
    short4v o;
    o[0] = f2bf(v.x); o[1] = f2bf(v.y); o[2] = f2bf(v.z); o[3] = f2bf(v.w);
    *(short4v*)(xb + i) = o;
    return;
  }

  if (u >= 5376) {
    // RoPE table: e = s*32 + dp, s in [0,2048), dp in [0,32)
    const int e = (u - 5376) * 256 + tid;
    const int s = e >> 5, dp = e & 31;
    const bool is_global = ((*layer_idx_p) % 3) == 0;
    const float theta = is_global ? 160000.0f : 10000.0f;
    const float nlt = -__logf(theta) * (1.0f / 64.0f);
    const float freq = __expf((float)(2 * dp) * nlt);
    float sn, cs;
    __sincosf((float)s * freq, &sn, &cs);
    float2 cssn; cssn.x = cs; cssn.y = sn;
    *(float2*)(tab + 2 * (size_t)e) = cssn;
    return;
  }

  const bool isqkv = (u < 4800);
  const float* in = isqkv ? Wqkv : Wout;
  short* out = isqkv ? Wqkvt : Woutt;
  const int C = isqkv ? N_QKV : ND;       // in cols
  const int tt = u - (isqkv ? 3072 : 4800);
  const int nbx = C / 32;
  const int bx = (tt % nbx) * 32;         // col base
  const int by = (tt / nbx) * 32;         // row base
  const int tx = tid & 31, ty = tid >> 5; // ty 0..7
#pragma unroll
  for (int i = 0; i < 32; i += 8)
    t[ty + i][tx] = in[(size_t)(by + ty + i) * C + bx + tx];
  __syncthreads();
#pragma unroll
  for (int i = 0; i < 32; i += 8)
    out[(size_t)(bx + ty + i) * ND + by + tx] = f2bf(t[tx][ty + i]);
}

// ---------------------------------------------------------------------------
// MFMA GEMM: 128x64 tile, BK=64, 4 waves each 32x64 via 2x4 16x16x32 bf16
// frags, global_load_lds width-16 staging, XOR-swizzled K-chunk LDS slots.
// XCD-aware tile swizzle (id&7 = XCD): each XCD owns a contiguous m-slab.
// MODE 0: qkv epilogue (bias + RoPE -> Qb/Kb [bh][s][64], V -> VT
//         [bh][64][s]).  MODE 1: plain fp32 out = acc + bias.
// R3: RoPE epilogue reads the precomputed {cos,sin} table (one 8B
// L2-resident load) instead of __expf + __sincosf per element.
// ---------------------------------------------------------------------------
template <int MODE>
__global__ __launch_bounds__(256) void mfma_gemm128_kernel(
    const short* __restrict__ A, const short* __restrict__ Bt,
    const float* __restrict__ bias, const float* __restrict__ tab,
    short* __restrict__ Qb, short* __restrict__ Kb, short* __restrict__ VT,
    float* __restrict__ Out, int K, int Ncols, int nTN, int mPerXcd)
{
  __shared__ short As[128 * 64];   // 16 KB
  __shared__ short Bs[64 * 64];    //  8 KB
  const int tid = threadIdx.x;
  const int w = tid >> 6, lane = tid & 63;
  const int c = lane & 15, g = lane >> 4;

  // XCD-aware swizzle: xcd = id&7 owns m-tiles [xcd*mPerXcd, ...+mPerXcd)
  const int id = blockIdx.x;
  const int xcd = id & 7;
  const int k = id >> 3;
  const int mt = xcd * mPerXcd + k / nTN;
  const int nt = k - (k / nTN) * nTN;
  const int bm = mt * 128, bn = nt * 64;

  const int lr = lane >> 3;            // staging row 0..7
  const int gch = (lane & 7) ^ lr;     // swizzled global K-chunk index

  float4v acc[2][4];
#pragma unroll
  for (int i = 0; i < 2; ++i)
#pragma unroll
    for (int j = 0; j < 4; ++j) acc[i][j] = (float4v){0.f, 0.f, 0.f, 0.f};

  const short* Ag = A + (size_t)(bm + w * 32 + lr) * K + gch * 8;
  const short* Bg = Bt + (size_t)(bn + w * 16 + lr) * K + gch * 8;
  short* AsW = As + (w * 32) * 64;     // wave-uniform LDS stage base
  short* BsW = Bs + (w * 16) * 64;

  const int cl7 = c & 7;
  const short* aw = As + (w * 32 + c) * 64;
  const short* bwp = Bs + c * 64;

  for (int k0 = 0; k0 < K; k0 += 64) {
    async_copy16(AsW,        Ag + k0);
    async_copy16(AsW + 512,  Ag + k0 + (size_t)8 * K);
    async_copy16(AsW + 1024, Ag + k0 + (size_t)16 * K);
    async_copy16(AsW + 1536, Ag + k0 + (size_t)24 * K);
    async_copy16(BsW,        Bg + k0);
    async_copy16(BsW + 512,  Bg + k0 + (size_t)8 * K);
    __syncthreads();   // drains vmcnt -> staged data visible

    short8 af[2][2], bfr[4][2];
#pragma unroll
    for (int t = 0; t < 2; ++t) {
      const int slot = ((t * 4 + g) ^ cl7) * 8;
#pragma unroll
      for (int i = 0; i < 2; ++i) af[i][t] = *(const short8*)(aw + i * 16 * 64 + slot);
#pragma unroll
      for (int j = 0; j < 4; ++j) bfr[j][t] = *(const short8*)(bwp + j * 16 * 64 + slot);
    }
#pragma unroll
    for (int t = 0; t < 2; ++t)
#pragma unroll
      for (int i = 0; i < 2; ++i)
#pragma unroll
        for (int j = 0; j < 4; ++j)
          acc[i][j] = __builtin_amdgcn_mfma_f32_16x16x32_bf16(af[i][t], bfr[j][t], acc[i][j], 0, 0, 0);
    __syncthreads();   // protect LDS before next stage
  }

  const int wm = bm + w * 32;
  const int wn = bn;
  float bj[4];
#pragma unroll
  for (int j = 0; j < 4; ++j) bj[j] = bias[wn + j * 16 + c];

  if (MODE == 1) {
#pragma unroll
    for (int i = 0; i < 2; ++i)
#pragma unroll
      for (int j = 0; j < 4; ++j)
#pragma unroll
        for (int r = 0; r < 4; ++r)
          Out[(size_t)(wm + i * 16 + 4 * g + r) * Ncols + wn + j * 16 + c] =
              acc[i][j][r] + bj[j];
  } else {
    const int which = bn / ND;               // uniform per block (768%64==0)
    const int hd0 = wn - which * ND;         // 64-aligned
    const int h = hd0 >> 6;
    const int bidx = bm >> 11;
    const int srow = (bm & (NS - 1)) + w * 32;

    if (which == 2) {
      // V: no RoPE; VT[bh][d][s], short4 along s
#pragma unroll
      for (int j = 0; j < 4; ++j) {
        const int d = j * 16 + c;
        short* vbase = VT + ((size_t)(bidx * NH + h) * HD + d) * NS;
#pragma unroll
        for (int i = 0; i < 2; ++i) {
          short4v v4;
#pragma unroll
          for (int r = 0; r < 4; ++r) v4[r] = f2bf(acc[i][j][r] + bj[j]);
          *(short4v*)(vbase + srow + i * 16 + 4 * g) = v4;
        }
      }
    } else {
      short* dst = which ? Kb : Qb;
      const bool oddc = (c & 1);
#pragma unroll
      for (int j = 0; j < 4; ++j) {
        const int d = j * 16 + c;
        const float* tj = tab + 2 * (size_t)(j * 8 + (c >> 1));  // + s*64
#pragma unroll
        for (int i = 0; i < 2; ++i) {
#pragma unroll
          for (int r = 0; r < 4; ++r) {
            const float val = acc[i][j][r] + bj[j];
            const float partner = __shfl_xor(val, 1);
            const int s = srow + i * 16 + 4 * g + r;
            const float2 cssn = *(const float2*)(tj + (size_t)s * 64);
            const float o = oddc ? (val * cssn.x + partner * cssn.y)
                                 : (val * cssn.x - partner * cssn.y);
            dst[((size_t)(bidx * NH + h) * NS + s) * HD + d] = f2bf(o);
          }
        }
      }
    }
  }
}

// ---------------------------------------------------------------------------
// MFMA banded flash attention (fixed-reference softmax). XCD-aware
// swizzle — each XCD owns 3 heads (K+V slab 1.5 MB -> L2-resident).
// (Exact R0 form — verified 146.6 µs base.)
// ---------------------------------------------------------------------------
__global__ __launch_bounds__(256) void attn_mfma_kernel(
    const short* __restrict__ Qb, const short* __restrict__ Kb,
    const short* __restrict__ VT, short* __restrict__ CTXb,
    const int* __restrict__ layer_idx_p)
{
  const int lane = threadIdx.x & 63;
  const int wv = threadIdx.x >> 6;
  const int c = lane & 15;
  const int g = lane >> 4;

  // swizzle: xcd = id&7 owns bh in [xcd*3, xcd*3+3)
  const int id = blockIdx.x;
  const int xcd = id & 7;
  const int k = id >> 3;               // 0..95
  const int bh = xcd * 3 + (k >> 5);
  const int qt = k & 31;

  const int b = bh / NH;
  const int h = bh - b * NH;
  const int q0 = qt * 64 + wv * 16;
  const bool is_global = ((*layer_idx_p) % 3) == 0;
  const size_t base = (size_t)bh * NS * HD;

  const short* qrow = Qb + base + (size_t)(q0 + c) * HD + g * 8;
  const short8 qf0 = *(const short8*)(qrow);
  const short8 qf1 = *(const short8*)(qrow + 32);

  float4v O0 = {0.f, 0.f, 0.f, 0.f}, O1 = O0, O2 = O0, O3 = O0;
  float lacc = 0.0f;
  const int q = q0 + c;

  const int lo = is_global ? 0 : q0 - 128;
  const int hi = is_global ? (NS - 1) : q0 + 143;

  for (int kt = lo; kt <= hi; kt += 32) {
    if (kt + 31 < 0 || kt >= NS) continue;

    const int k1c = min(max(kt + c, 0), NS - 1);
    const int k2c = min(max(kt + 16 + c, 0), NS - 1);
    const short* kr1 = Kb + base + (size_t)k1c * HD + g * 8;
    const short* kr2 = Kb + base + (size_t)k2c * HD + g * 8;
    const short8 kf10 = *(const short8*)kr1;
    const short8 kf11 = *(const short8*)(kr1 + 32);
    const short8 kf20 = *(const short8*)kr2;
    const short8 kf21 = *(const short8*)(kr2 + 32);
    float4v st1 = {0.f, 0.f, 0.f, 0.f}, st2 = {0.f, 0.f, 0.f, 0.f};
    st1 = __builtin_amdgcn_mfma_f32_16x16x32_bf16(kf10, qf0, st1, 0, 0, 0);
    st1 = __builtin_amdgcn_mfma_f32_16x16x32_bf16(kf11, qf1, st1, 0, 0, 0);
    st2 = __builtin_amdgcn_mfma_f32_16x16x32_bf16(kf20, qf0, st2, 0, 0, 0);
    st2 = __builtin_amdgcn_mfma_f32_16x16x32_bf16(kf21, qf1, st2, 0, 0, 0);

    float p1[4], p2[4];
#pragma unroll
    for (int r = 0; r < 4; ++r) {
      const int key1 = kt + 4 * g + r;
      const int key2 = key1 + 16;
      const bool v1 = (key1 >= 0) & (key1 < NS) &
                      (is_global | ((key1 - q <= WIN) & (q - key1 <= WIN)));
      const bool v2 = (key2 >= 0) & (key2 < NS) &
                      (is_global | ((key2 - q <= WIN) & (q - key2 <= WIN)));
      p1[r] = __expf(v1 ? st1[r] * 0.125f : -1e30f);
      p2[r] = __expf(v2 ? st2[r] * 0.125f : -1e30f);
      lacc += p1[r] + p2[r];
    }

    const int srcA = (2 * (g & 1)) * 16 + c;
    const int srcB = srcA + 16;
    short8 pf;
#pragma unroll
    for (int r = 0; r < 4; ++r) {
      const float f1a = __shfl(p1[r], srcA);
      const float f1b = __shfl(p1[r], srcB);
      const float f2a = __shfl(p2[r], srcA);
      const float f2b = __shfl(p2[r], srcB);
      pf[r]     = f2bf((g < 2) ? f1a : f2a);
      pf[4 + r] = f2bf((g < 2) ? f1b : f2b);
    }

    const int ks = min(max(kt + 8 * g, 0), NS - 8);
    const short* vrow = VT + base + (size_t)c * NS + ks;
    const short8 vf0 = *(const short8*)(vrow);
    const short8 vf1 = *(const short8*)(vrow + 16 * NS);
    const short8 vf2 = *(const short8*)(vrow + 32 * NS);
    const short8 vf3 = *(const short8*)(vrow + 48 * NS);
    O0 = __builtin_amdgcn_mfma_f32_16x16x32_bf16(vf0, pf, O0, 0, 0, 0);
    O1 = __builtin_amdgcn_mfma_f32_16x16x32_bf16(vf1, pf, O1, 0, 0, 0);
    O2 = __builtin_amdgcn_mfma_f32_16x16x32_bf16(vf2, pf, O2, 0, 0, 0);
    O3 = __builtin_amdgcn_mfma_f32_16x16x32_bf16(vf3, pf, O3, 0, 0, 0);
  }

  // epilogue: one cross-quad reduction of l, then scale+store
  lacc += __shfl_xor(lacc, 16);
  lacc += __shfl_xor(lacc, 32);
  const float inv = 1.0f / lacc;
  short* crow = CTXb + ((size_t)(b * NS + q) * NH + h) * HD;
#pragma unroll
  for (int r = 0; r < 4; ++r) {
    const int d = 4 * g + r;
    crow[d]      = f2bf(O0[r] * inv);
    crow[d + 16] = f2bf(O1[r] * inv);
    crow[d + 32] = f2bf(O2[r] * inv);
    crow[d + 48] = f2bf(O3[r] * inv);
  }
}

// ---------------------------------------------------------------------------
extern "C" void kernel_launch(void* const* d_in, const int* in_sizes, int n_in,
                              void* d_out, int out_size, void* d_ws, size_t ws_size,
                              hipStream_t stream) {
  const float* x    = (const float*)d_in[0];
  const float* Wqkv = (const float*)d_in[1];
  const float* bqkv = (const float*)d_in[2];
  const float* Wout = (const float*)d_in[3];
  const float* bout = (const float*)d_in[4];
  const int* layer_idx = (const int*)d_in[5];

  short* xb    = (short*)d_ws;                         // [4096][768]
  short* Wqkvt = xb + (size_t)NB * NS * ND;            // [2304][768]
  short* Woutt = Wqkvt + (size_t)ND * N_QKV;           // [768][768]
  short* Qb    = Woutt + (size_t)ND * ND;              // [bh][s][64]
  short* Kb    = Qb + (size_t)QKN;
  short* VT    = Kb + (size_t)QKN;                     // [bh][64][s]
  short* CTXb  = VT + (size_t)QKN;                     // [4096][768]
  float* tab   = (float*)(CTXb + (size_t)NB * NS * ND); // [2048][32][2] f32, 512 KB
  // total: 18087936 shorts + 512 KB = 36.7 MB

  // phase 0: all preps in one dispatch (+256 blocks for the RoPE table)
  prep_kernel<<<5632, 256, 0, stream>>>(x, Wqkv, Wout, layer_idx, xb, Wqkvt, Woutt, tab);

  // QKV GEMM + RoPE: M=4096, N=2304, K=768. 32 m-tiles x 36 n-tiles = 1152.
  mfma_gemm128_kernel<0><<<1152, 256, 0, stream>>>(
      xb, Wqkvt, bqkv, tab, Qb, Kb, VT, nullptr, ND, N_QKV, 36, 4);

  attn_mfma_kernel<<<NB * NH * (NS / 64), 256, 0, stream>>>(Qb, Kb, VT, CTXb, layer_idx);

  // Out projection: M=4096, N=768, K=768. 32 m-tiles x 12 n-tiles = 384.
  mfma_gemm128_kernel<1><<<384, 256, 0, stream>>>(
      CTXb, Woutt, bout, nullptr, nullptr, nullptr, nullptr, (float*)d_out, ND, ND, 12, 4);
}

// Round 4
// 149.250 us; speedup vs baseline: 1.0723x; 1.0089x over previous
//
#include <hip/hip_runtime.h>
#include <hip/hip_bf16.h>
#include <math.h>

#define NB 2
#define NS 2048
#define ND 768
#define NH 12
#define HD 64
#define WIN 128
#define N_QKV 2304
#define QKN (NB * NH * NS * HD)   // 3145728

typedef __attribute__((ext_vector_type(8))) short short8;
typedef __attribute__((ext_vector_type(4))) short short4v;
typedef __attribute__((ext_vector_type(4))) float float4v;

static __device__ __forceinline__ short f2bf(float f) {
  __hip_bfloat16 h = __float2bfloat16(f);
  short s;
  __builtin_memcpy(&s, &h, 2);
  return s;
}

static __device__ __forceinline__ void async_copy16(void* lds, const void* g) {
  __builtin_amdgcn_global_load_lds(
      (const __attribute__((address_space(1))) unsigned int*)g,
      (__attribute__((address_space(3))) unsigned int*)(unsigned int)(unsigned long long)lds,
      16, 0, 0);
}

// ---------------------------------------------------------------------------
// Merged prep kernel: x cvt (3072 units) + Wqkv^T (1728) + Wout^T (576).
// (Exact R0 form.)
// ---------------------------------------------------------------------------
__global__ __launch_bounds__(256) void prep_kernel(
    const float* __restrict__ x, const float* __restrict__ Wqkv,
    const float* __restrict__ Wout, short* __restrict__ xb,
    short* __restrict__ Wqkvt, short* __restrict__ Woutt)
{
  __shared__ float t[32][33];
  const int u = blockIdx.x;
  const int tid = threadIdx.x;

  if (u < 3072) {
    const int i = u * 1024 + tid * 4;
    const float4 v = *(const float4*)(x + i);
    short4v o;
    o[0] = f2bf(v.x); o[1] = f2bf(v.y); o[2] = f2bf(v.z); o[3] = f2bf(v.w);
    *(short4v*)(xb + i) = o;
    return;
  }

  const bool isqkv = (u < 4800);
  const float* in = isqkv ? Wqkv : Wout;
  short* out = isqkv ? Wqkvt : Woutt;
  const int C = isqkv ? N_QKV : ND;       // in cols
  const int tt = u - (isqkv ? 3072 : 4800);
  const int nbx = C / 32;
  const int bx = (tt % nbx) * 32;         // col base
  const int by = (tt / nbx) * 32;         // row base
  const int tx = tid & 31, ty = tid >> 5; // ty 0..7
#pragma unroll
  for (int i = 0; i < 32; i += 8)
    t[ty + i][tx] = in[(size_t)(by + ty + i) * C + bx + tx];
  __syncthreads();
#pragma unroll
  for (int i = 0; i < 32; i += 8)
    out[(size_t)(bx + ty + i) * ND + by + tx] = f2bf(t[tx][ty + i]);
}

// ---------------------------------------------------------------------------
// MFMA GEMM: 128x64 tile, BK=64, 4 waves each 32x64 via 2x4 16x16x32 bf16
// frags, global_load_lds width-16 staging, XOR-swizzled K-chunk LDS slots.
// XCD-aware tile swizzle. MODE 0: qkv epilogue (bias + RoPE -> Qb/Kb
// [bh][s][64], V -> VT [bh][64][s]). MODE 1: plain fp32 out = acc + bias.
// (Exact R0 form — sincos epilogue; R3's table was a -4us regression.)
// ---------------------------------------------------------------------------
template <int MODE>
__global__ __launch_bounds__(256) void mfma_gemm128_kernel(
    const short* __restrict__ A, const short* __restrict__ Bt,
    const float* __restrict__ bias, const int* __restrict__ layer_idx_p,
    short* __restrict__ Qb, short* __restrict__ Kb, short* __restrict__ VT,
    float* __restrict__ Out, int K, int Ncols, int nTN, int mPerXcd)
{
  __shared__ short As[128 * 64];   // 16 KB
  __shared__ short Bs[64 * 64];    //  8 KB
  const int tid = threadIdx.x;
  const int w = tid >> 6, lane = tid & 63;
  const int c = lane & 15, g = lane >> 4;

  const int id = blockIdx.x;
  const int xcd = id & 7;
  const int k = id >> 3;
  const int mt = xcd * mPerXcd + k / nTN;
  const int nt = k - (k / nTN) * nTN;
  const int bm = mt * 128, bn = nt * 64;

  const int lr = lane >> 3;            // staging row 0..7
  const int gch = (lane & 7) ^ lr;     // swizzled global K-chunk index

  float4v acc[2][4];
#pragma unroll
  for (int i = 0; i < 2; ++i)
#pragma unroll
    for (int j = 0; j < 4; ++j) acc[i][j] = (float4v){0.f, 0.f, 0.f, 0.f};

  const short* Ag = A + (size_t)(bm + w * 32 + lr) * K + gch * 8;
  const short* Bg = Bt + (size_t)(bn + w * 16 + lr) * K + gch * 8;
  short* AsW = As + (w * 32) * 64;     // wave-uniform LDS stage base
  short* BsW = Bs + (w * 16) * 64;

  const int cl7 = c & 7;
  const short* aw = As + (w * 32 + c) * 64;
  const short* bwp = Bs + c * 64;

  for (int k0 = 0; k0 < K; k0 += 64) {
    async_copy16(AsW,        Ag + k0);
    async_copy16(AsW + 512,  Ag + k0 + (size_t)8 * K);
    async_copy16(AsW + 1024, Ag + k0 + (size_t)16 * K);
    async_copy16(AsW + 1536, Ag + k0 + (size_t)24 * K);
    async_copy16(BsW,        Bg + k0);
    async_copy16(BsW + 512,  Bg + k0 + (size_t)8 * K);
    __syncthreads();   // drains vmcnt -> staged data visible

    short8 af[2][2], bfr[4][2];
#pragma unroll
    for (int t = 0; t < 2; ++t) {
      const int slot = ((t * 4 + g) ^ cl7) * 8;
#pragma unroll
      for (int i = 0; i < 2; ++i) af[i][t] = *(const short8*)(aw + i * 16 * 64 + slot);
#pragma unroll
      for (int j = 0; j < 4; ++j) bfr[j][t] = *(const short8*)(bwp + j * 16 * 64 + slot);
    }
#pragma unroll
    for (int t = 0; t < 2; ++t)
#pragma unroll
      for (int i = 0; i < 2; ++i)
#pragma unroll
        for (int j = 0; j < 4; ++j)
          acc[i][j] = __builtin_amdgcn_mfma_f32_16x16x32_bf16(af[i][t], bfr[j][t], acc[i][j], 0, 0, 0);
    __syncthreads();   // protect LDS before next stage
  }

  const int wm = bm + w * 32;
  const int wn = bn;
  float bj[4];
#pragma unroll
  for (int j = 0; j < 4; ++j) bj[j] = bias[wn + j * 16 + c];

  if (MODE == 1) {
#pragma unroll
    for (int i = 0; i < 2; ++i)
#pragma unroll
      for (int j = 0; j < 4; ++j)
#pragma unroll
        for (int r = 0; r < 4; ++r)
          Out[(size_t)(wm + i * 16 + 4 * g + r) * Ncols + wn + j * 16 + c] =
              acc[i][j][r] + bj[j];
  } else {
    const int which = bn / ND;               // uniform per block (768%64==0)
    const int hd0 = wn - which * ND;         // 64-aligned
    const int h = hd0 >> 6;
    const int bidx = bm >> 11;
    const int srow = (bm & (NS - 1)) + w * 32;

    if (which == 2) {
      // V: no RoPE; VT[bh][d][s], short4 along s
#pragma unroll
      for (int j = 0; j < 4; ++j) {
        const int d = j * 16 + c;
        short* vbase = VT + ((size_t)(bidx * NH + h) * HD + d) * NS;
#pragma unroll
        for (int i = 0; i < 2; ++i) {
          short4v v4;
#pragma unroll
          for (int r = 0; r < 4; ++r) v4[r] = f2bf(acc[i][j][r] + bj[j]);
          *(short4v*)(vbase + srow + i * 16 + 4 * g) = v4;
        }
      }
    } else {
      const bool is_global = ((*layer_idx_p) % 3) == 0;
      const float theta = is_global ? 160000.0f : 10000.0f;
      const float nlt = -__logf(theta) * (1.0f / 64.0f);
      short* dst = which ? Kb : Qb;
      const bool oddc = (c & 1);
#pragma unroll
      for (int j = 0; j < 4; ++j) {
        const int d = j * 16 + c;
        const float freq = __expf((float)(d & ~1) * nlt);
#pragma unroll
        for (int i = 0; i < 2; ++i) {
#pragma unroll
          for (int r = 0; r < 4; ++r) {
            const float val = acc[i][j][r] + bj[j];
            const float partner = __shfl_xor(val, 1);
            const int s = srow + i * 16 + 4 * g + r;
            float sn, cs;
            __sincosf((float)s * freq, &sn, &cs);
            const float o = oddc ? (val * cs + partner * sn)
                                 : (val * cs - partner * sn);
            dst[((size_t)(bidx * NH + h) * NS + s) * HD + d] = f2bf(o);
          }
        }
      }
    }
  }
}

// ---------------------------------------------------------------------------
// MFMA banded flash attention (fixed-reference softmax). XCD-aware swizzle.
// R4: the LOCAL (timed) path is a branch-free, compile-time 9-tile loop,
// fully unrolled -> scheduler can pipeline tile t+1's K/V loads under tile
// t's MFMA/exp/shfl. Out-of-range tiles are computed but masked: clamped
// load indices + window mask give exp(-1e30)=0 -> exact +0.0 to lacc/acc,
// so the output is bit-identical to the skipping loop.
// Global path keeps the dynamic loop (correctness-only; layer_idx=1 timed).
// ---------------------------------------------------------------------------
#define ATTN_TILE(KT, ISG)                                                     \
  do {                                                                         \
    const int kt = (KT);                                                       \
    const int k1c = min(max(kt + c, 0), NS - 1);                               \
    const int k2c = min(max(kt + 16 + c, 0), NS - 1);                          \
    const short* kr1 = Kb + base + (size_t)k1c * HD + g * 8;                   \
    const short* kr2 = Kb + base + (size_t)k2c * HD + g * 8;                   \
    const short8 kf10 = *(const short8*)kr1;                                   \
    const short8 kf11 = *(const short8*)(kr1 + 32);                            \
    const short8 kf20 = *(const short8*)kr2;                                   \
    const short8 kf21 = *(const short8*)(kr2 + 32);                            \
    float4v st1 = {0.f, 0.f, 0.f, 0.f}, st2 = {0.f, 0.f, 0.f, 0.f};            \
    st1 = __builtin_amdgcn_mfma_f32_16x16x32_bf16(kf10, qf0, st1, 0, 0, 0);    \
    st1 = __builtin_amdgcn_mfma_f32_16x16x32_bf16(kf11, qf1, st1, 0, 0, 0);    \
    st2 = __builtin_amdgcn_mfma_f32_16x16x32_bf16(kf20, qf0, st2, 0, 0, 0);    \
    st2 = __builtin_amdgcn_mfma_f32_16x16x32_bf16(kf21, qf1, st2, 0, 0, 0);    \
    float p1[4], p2[4];                                                        \
    _Pragma("unroll")                                                          \
    for (int r = 0; r < 4; ++r) {                                              \
      const int key1 = kt + 4 * g + r;                                         \
      const int key2 = key1 + 16;                                              \
      const bool v1 = (key1 >= 0) & (key1 < NS) &                              \
                      ((ISG) | ((key1 - q <= WIN) & (q - key1 <= WIN)));       \
      const bool v2 = (key2 >= 0) & (key2 < NS) &                              \
                      ((ISG) | ((key2 - q <= WIN) & (q - key2 <= WIN)));       \
      p1[r] = __expf(v1 ? st1[r] * 0.125f : -1e30f);                           \
      p2[r] = __expf(v2 ? st2[r] * 0.125f : -1e30f);                           \
      lacc += p1[r] + p2[r];                                                   \
    }                                                                          \
    const int srcA = (2 * (g & 1)) * 16 + c;                                   \
    const int srcB = srcA + 16;                                                \
    short8 pf;                                                                 \
    _Pragma("unroll")                                                          \
    for (int r = 0; r < 4; ++r) {                                              \
      const float f1a = __shfl(p1[r], srcA);                                   \
      const float f1b = __shfl(p1[r], srcB);                                   \
      const float f2a = __shfl(p2[r], srcA);                                   \
      const float f2b = __shfl(p2[r], srcB);                                   \
      pf[r]     = f2bf((g < 2) ? f1a : f2a);                                   \
      pf[4 + r] = f2bf((g < 2) ? f1b : f2b);                                   \
    }                                                                          \
    const int ks = min(max(kt + 8 * g, 0), NS - 8);                            \
    const short* vrow = VT + base + (size_t)c * NS + ks;                       \
    const short8 vf0 = *(const short8*)(vrow);                                 \
    const short8 vf1 = *(const short8*)(vrow + 16 * NS);                       \
    const short8 vf2 = *(const short8*)(vrow + 32 * NS);                       \
    const short8 vf3 = *(const short8*)(vrow + 48 * NS);                       \
    O0 = __builtin_amdgcn_mfma_f32_16x16x32_bf16(vf0, pf, O0, 0, 0, 0);        \
    O1 = __builtin_amdgcn_mfma_f32_16x16x32_bf16(vf1, pf, O1, 0, 0, 0);        \
    O2 = __builtin_amdgcn_mfma_f32_16x16x32_bf16(vf2, pf, O2, 0, 0, 0);        \
    O3 = __builtin_amdgcn_mfma_f32_16x16x32_bf16(vf3, pf, O3, 0, 0, 0);        \
  } while (0)

__global__ __launch_bounds__(256) void attn_mfma_kernel(
    const short* __restrict__ Qb, const short* __restrict__ Kb,
    const short* __restrict__ VT, short* __restrict__ CTXb,
    const int* __restrict__ layer_idx_p)
{
  const int lane = threadIdx.x & 63;
  const int wv = threadIdx.x >> 6;
  const int c = lane & 15;
  const int g = lane >> 4;

  // swizzle: xcd = id&7 owns bh in [xcd*3, xcd*3+3)
  const int id = blockIdx.x;
  const int xcd = id & 7;
  const int k = id >> 3;               // 0..95
  const int bh = xcd * 3 + (k >> 5);
  const int qt = k & 31;

  const int b = bh / NH;
  const int h = bh - b * NH;
  const int q0 = qt * 64 + wv * 16;
  const bool is_global = ((*layer_idx_p) % 3) == 0;
  const size_t base = (size_t)bh * NS * HD;

  const short* qrow = Qb + base + (size_t)(q0 + c) * HD + g * 8;
  const short8 qf0 = *(const short8*)(qrow);
  const short8 qf1 = *(const short8*)(qrow + 32);

  float4v O0 = {0.f, 0.f, 0.f, 0.f}, O1 = O0, O2 = O0, O3 = O0;
  float lacc = 0.0f;
  const int q = q0 + c;

  if (!is_global) {
    // local: constant 9 tiles (kt = q0-128 .. q0+128), branch-free, unrolled
#pragma unroll
    for (int t = 0; t < 9; ++t) {
      ATTN_TILE(q0 - 128 + t * 32, false);
    }
  } else {
    for (int kt = 0; kt < NS; kt += 32) {
      ATTN_TILE(kt, true);
    }
  }

  // epilogue: one cross-quad reduction of l, then scale+store
  lacc += __shfl_xor(lacc, 16);
  lacc += __shfl_xor(lacc, 32);
  const float inv = 1.0f / lacc;
  short* crow = CTXb + ((size_t)(b * NS + q) * NH + h) * HD;
#pragma unroll
  for (int r = 0; r < 4; ++r) {
    const int d = 4 * g + r;
    crow[d]      = f2bf(O0[r] * inv);
    crow[d + 16] = f2bf(O1[r] * inv);
    crow[d + 32] = f2bf(O2[r] * inv);
    crow[d + 48] = f2bf(O3[r] * inv);
  }
}

// ---------------------------------------------------------------------------
extern "C" void kernel_launch(void* const* d_in, const int* in_sizes, int n_in,
                              void* d_out, int out_size, void* d_ws, size_t ws_size,
                              hipStream_t stream) {
  const float* x    = (const float*)d_in[0];
  const float* Wqkv = (const float*)d_in[1];
  const float* bqkv = (const float*)d_in[2];
  const float* Wout = (const float*)d_in[3];
  const float* bout = (const float*)d_in[4];
  const int* layer_idx = (const int*)d_in[5];

  short* xb    = (short*)d_ws;                         // [4096][768]
  short* Wqkvt = xb + (size_t)NB * NS * ND;            // [2304][768]
  short* Woutt = Wqkvt + (size_t)ND * N_QKV;           // [768][768]
  short* Qb    = Woutt + (size_t)ND * ND;              // [bh][s][64]
  short* Kb    = Qb + (size_t)QKN;
  short* VT    = Kb + (size_t)QKN;                     // [bh][64][s]
  short* CTXb  = VT + (size_t)QKN;                     // [4096][768]
  // total: 18087936 shorts = 36.2 MB

  // phase 0: all preps in one dispatch
  prep_kernel<<<5376, 256, 0, stream>>>(x, Wqkv, Wout, xb, Wqkvt, Woutt);

  // QKV GEMM + RoPE: M=4096, N=2304, K=768. 32 m-tiles x 36 n-tiles = 1152.
  mfma_gemm128_kernel<0><<<1152, 256, 0, stream>>>(
      xb, Wqkvt, bqkv, layer_idx, Qb, Kb, VT, nullptr, ND, N_QKV, 36, 4);

  attn_mfma_kernel<<<NB * NH * (NS / 64), 256, 0, stream>>>(Qb, Kb, VT, CTXb, layer_idx);

  // Out projection: M=4096, N=768, K=768. 32 m-tiles x 12 n-tiles = 384.
  mfma_gemm128_kernel<1><<<384, 256, 0, stream>>>(
      CTXb, Woutt, bout, layer_idx, nullptr, nullptr, nullptr, (float*)d_out, ND, ND, 12, 4);
}

// Round 9
// 147.939 us; speedup vs baseline: 1.0819x; 1.0089x over previous
//
#include <hip/hip_runtime.h>
#include <hip/hip_bf16.h>
#include <math.h>

#define NB 2
#define NS 2048
#define ND 768
#define NH 12
#define HD 64
#define WIN 128
#define N_QKV 2304
#define QKN (NB * NH * NS * HD)   // 3145728

typedef __attribute__((ext_vector_type(8))) short short8;
typedef __attribute__((ext_vector_type(4))) short short4v;
typedef __attribute__((ext_vector_type(4))) float float4v;

static __device__ __forceinline__ short f2bf(float f) {
  __hip_bfloat16 h = __float2bfloat16(f);
  short s;
  __builtin_memcpy(&s, &h, 2);
  return s;
}

static __device__ __forceinline__ void async_copy16(void* lds, const void* g) {
  __builtin_amdgcn_global_load_lds(
      (const __attribute__((address_space(1))) unsigned int*)g,
      (__attribute__((address_space(3))) unsigned int*)(unsigned int)(unsigned long long)lds,
      16, 0, 0);
}

// ---------------------------------------------------------------------------
// Merged prep kernel: x cvt (3072 units) + Wqkv^T (1728) + Wout^T (576).
// (Exact R0 form.)
// ---------------------------------------------------------------------------
__global__ __launch_bounds__(256) void prep_kernel(
    const float* __restrict__ x, const float* __restrict__ Wqkv,
    const float* __restrict__ Wout, short* __restrict__ xb,
    short* __restrict__ Wqkvt, short* __restrict__ Woutt)
{
  __shared__ float t[32][33];
  const int u = blockIdx.x;
  const int tid = threadIdx.x;

  if (u < 3072) {
    const int i = u * 1024 + tid * 4;
    const float4 v = *(const float4*)(x + i);
    short4v o;
    o[0] = f2bf(v.x); o[1] = f2bf(v.y); o[2] = f2bf(v.z); o[3] = f2bf(v.w);
    *(short4v*)(xb + i) = o;
    return;
  }

  const bool isqkv = (u < 4800);
  const float* in = isqkv ? Wqkv : Wout;
  short* out = isqkv ? Wqkvt : Woutt;
  const int C = isqkv ? N_QKV : ND;       // in cols
  const int tt = u - (isqkv ? 3072 : 4800);
  const int nbx = C / 32;
  const int bx = (tt % nbx) * 32;         // col base
  const int by = (tt / nbx) * 32;         // row base
  const int tx = tid & 31, ty = tid >> 5; // ty 0..7
#pragma unroll
  for (int i = 0; i < 32; i += 8)
    t[ty + i][tx] = in[(size_t)(by + ty + i) * C + bx + tx];
  __syncthreads();
#pragma unroll
  for (int i = 0; i < 32; i += 8)
    out[(size_t)(bx + ty + i) * ND + by + tx] = f2bf(t[tx][ty + i]);
}

// ---------------------------------------------------------------------------
// MFMA GEMM: 128x64 tile, BK=64, 4 waves each 32x64 via 2x4 16x16x32 bf16
// frags, global_load_lds width-16 staging, XOR-swizzled K-chunk LDS slots.
// XCD-aware tile swizzle. MODE 0: qkv epilogue (bias + RoPE -> Qb/Kb
// [bh][s][64], V -> VT [bh][64][s]). MODE 1: plain fp32 out = acc + bias.
// (Exact R0 form.)
// ---------------------------------------------------------------------------
template <int MODE>
__global__ __launch_bounds__(256) void mfma_gemm128_kernel(
    const short* __restrict__ A, const short* __restrict__ Bt,
    const float* __restrict__ bias, const int* __restrict__ layer_idx_p,
    short* __restrict__ Qb, short* __restrict__ Kb, short* __restrict__ VT,
    float* __restrict__ Out, int K, int Ncols, int nTN, int mPerXcd)
{
  __shared__ short As[128 * 64];   // 16 KB
  __shared__ short Bs[64 * 64];    //  8 KB
  const int tid = threadIdx.x;
  const int w = tid >> 6, lane = tid & 63;
  const int c = lane & 15, g = lane >> 4;

  const int id = blockIdx.x;
  const int xcd = id & 7;
  const int k = id >> 3;
  const int mt = xcd * mPerXcd + k / nTN;
  const int nt = k - (k / nTN) * nTN;
  const int bm = mt * 128, bn = nt * 64;

  const int lr = lane >> 3;            // staging row 0..7
  const int gch = (lane & 7) ^ lr;     // swizzled global K-chunk index

  float4v acc[2][4];
#pragma unroll
  for (int i = 0; i < 2; ++i)
#pragma unroll
    for (int j = 0; j < 4; ++j) acc[i][j] = (float4v){0.f, 0.f, 0.f, 0.f};

  const short* Ag = A + (size_t)(bm + w * 32 + lr) * K + gch * 8;
  const short* Bg = Bt + (size_t)(bn + w * 16 + lr) * K + gch * 8;
  short* AsW = As + (w * 32) * 64;     // wave-uniform LDS stage base
  short* BsW = Bs + (w * 16) * 64;

  const int cl7 = c & 7;
  const short* aw = As + (w * 32 + c) * 64;
  const short* bwp = Bs + c * 64;

  for (int k0 = 0; k0 < K; k0 += 64) {
    async_copy16(AsW,        Ag + k0);
    async_copy16(AsW + 512,  Ag + k0 + (size_t)8 * K);
    async_copy16(AsW + 1024, Ag + k0 + (size_t)16 * K);
    async_copy16(AsW + 1536, Ag + k0 + (size_t)24 * K);
    async_copy16(BsW,        Bg + k0);
    async_copy16(BsW + 512,  Bg + k0 + (size_t)8 * K);
    __syncthreads();   // drains vmcnt -> staged data visible

    short8 af[2][2], bfr[4][2];
#pragma unroll
    for (int t = 0; t < 2; ++t) {
      const int slot = ((t * 4 + g) ^ cl7) * 8;
#pragma unroll
      for (int i = 0; i < 2; ++i) af[i][t] = *(const short8*)(aw + i * 16 * 64 + slot);
#pragma unroll
      for (int j = 0; j < 4; ++j) bfr[j][t] = *(const short8*)(bwp + j * 16 * 64 + slot);
    }
#pragma unroll
    for (int t = 0; t < 2; ++t)
#pragma unroll
      for (int i = 0; i < 2; ++i)
#pragma unroll
        for (int j = 0; j < 4; ++j)
          acc[i][j] = __builtin_amdgcn_mfma_f32_16x16x32_bf16(af[i][t], bfr[j][t], acc[i][j], 0, 0, 0);
    __syncthreads();   // protect LDS before next stage
  }

  const int wm = bm + w * 32;
  const int wn = bn;
  float bj[4];
#pragma unroll
  for (int j = 0; j < 4; ++j) bj[j] = bias[wn + j * 16 + c];

  if (MODE == 1) {
#pragma unroll
    for (int i = 0; i < 2; ++i)
#pragma unroll
      for (int j = 0; j < 4; ++j)
#pragma unroll
        for (int r = 0; r < 4; ++r)
          Out[(size_t)(wm + i * 16 + 4 * g + r) * Ncols + wn + j * 16 + c] =
              acc[i][j][r] + bj[j];
  } else {
    const int which = bn / ND;               // uniform per block (768%64==0)
    const int hd0 = wn - which * ND;         // 64-aligned
    const int h = hd0 >> 6;
    const int bidx = bm >> 11;
    const int srow = (bm & (NS - 1)) + w * 32;

    if (which == 2) {
      // V: no RoPE; VT[bh][d][s], short4 along s
#pragma unroll
      for (int j = 0; j < 4; ++j) {
        const int d = j * 16 + c;
        short* vbase = VT + ((size_t)(bidx * NH + h) * HD + d) * NS;
#pragma unroll
        for (int i = 0; i < 2; ++i) {
          short4v v4;
#pragma unroll
          for (int r = 0; r < 4; ++r) v4[r] = f2bf(acc[i][j][r] + bj[j]);
          *(short4v*)(vbase + srow + i * 16 + 4 * g) = v4;
        }
      }
    } else {
      const bool is_global = ((*layer_idx_p) % 3) == 0;
      const float theta = is_global ? 160000.0f : 10000.0f;
      const float nlt = -__logf(theta) * (1.0f / 64.0f);
      short* dst = which ? Kb : Qb;
      const bool oddc = (c & 1);
#pragma unroll
      for (int j = 0; j < 4; ++j) {
        const int d = j * 16 + c;
        const float freq = __expf((float)(d & ~1) * nlt);
#pragma unroll
        for (int i = 0; i < 2; ++i) {
#pragma unroll
          for (int r = 0; r < 4; ++r) {
            const float val = acc[i][j][r] + bj[j];
            const float partner = __shfl_xor(val, 1);
            const int s = srow + i * 16 + 4 * g + r;
            float sn, cs;
            __sincosf((float)s * freq, &sn, &cs);
            const float o = oddc ? (val * cs + partner * sn)
                                 : (val * cs - partner * sn);
            dst[((size_t)(bidx * NH + h) * NS + s) * HD + d] = f2bf(o);
          }
        }
      }
    }
  }
}

// ---------------------------------------------------------------------------
// MFMA banded flash attention. XCD-aware swizzle (each XCD owns 3 heads).
// R5-R9: split-K across wave halves. 512 threads = 8 waves; waves 0-3
// process key-tiles [q0-128..q0] (5), waves 4-7 process [q0+32..q0+128] (4)
// for the SAME 64 q-rows. Fixed-reference softmax -> merge is a pure add of
// (O, l) partials through LDS + one __syncthreads. Per-wave serial chain
// 9->5 tiles; resident waves/CU 12->16. Tile body is exactly R0's.
// ---------------------------------------------------------------------------
__global__ __launch_bounds__(512) void attn_mfma_kernel(
    const short* __restrict__ Qb, const short* __restrict__ Kb,
    const short* __restrict__ VT, short* __restrict__ CTXb,
    const int* __restrict__ layer_idx_p)
{
  __shared__ float red[8][17][64];     // [wave][O 0..15, l=16][lane]
  const int tid = threadIdx.x;
  const int lane = tid & 63;
  const int wv = tid >> 6;             // 0..7
  const int half = wv >> 2;            // 0: front tiles, 1: back tiles
  const int wq = wv & 3;               // q-subtile within the 64-row block
  const int c = lane & 15;
  const int g = lane >> 4;

  // swizzle: xcd = id&7 owns bh in [xcd*3, xcd*3+3)
  const int id = blockIdx.x;
  const int xcd = id & 7;
  const int k = id >> 3;               // 0..95
  const int bh = xcd * 3 + (k >> 5);
  const int qt = k & 31;

  const int b = bh / NH;
  const int h = bh - b * NH;
  const int q0 = qt * 64 + wq * 16;
  const bool is_global = ((*layer_idx_p) % 3) == 0;
  const size_t base = (size_t)bh * NS * HD;

  const short* qrow = Qb + base + (size_t)(q0 + c) * HD + g * 8;
  const short8 qf0 = *(const short8*)(qrow);
  const short8 qf1 = *(const short8*)(qrow + 32);

  float4v O0 = {0.f, 0.f, 0.f, 0.f}, O1 = O0, O2 = O0, O3 = O0;
  float lacc = 0.0f;
  const int q = q0 + c;

  int lo, hi;
  if (!is_global) {
    lo = half ? (q0 + 32)  : (q0 - 128);
    hi = half ? (q0 + 128) : (q0);
  } else {
    lo = half ? (NS / 2)      : 0;
    hi = half ? (NS - 32)     : (NS / 2 - 32);
  }

  for (int kt = lo; kt <= hi; kt += 32) {
    if (kt + 31 < 0 || kt >= NS) continue;

    const int k1c = min(max(kt + c, 0), NS - 1);
    const int k2c = min(max(kt + 16 + c, 0), NS - 1);
    const short* kr1 = Kb + base + (size_t)k1c * HD + g * 8;
    const short* kr2 = Kb + base + (size_t)k2c * HD + g * 8;
    const short8 kf10 = *(const short8*)kr1;
    const short8 kf11 = *(const short8*)(kr1 + 32);
    const short8 kf20 = *(const short8*)kr2;
    const short8 kf21 = *(const short8*)(kr2 + 32);
    float4v st1 = {0.f, 0.f, 0.f, 0.f}, st2 = {0.f, 0.f, 0.f, 0.f};
    st1 = __builtin_amdgcn_mfma_f32_16x16x32_bf16(kf10, qf0, st1, 0, 0, 0);
    st1 = __builtin_amdgcn_mfma_f32_16x16x32_bf16(kf11, qf1, st1, 0, 0, 0);
    st2 = __builtin_amdgcn_mfma_f32_16x16x32_bf16(kf20, qf0, st2, 0, 0, 0);
    st2 = __builtin_amdgcn_mfma_f32_16x16x32_bf16(kf21, qf1, st2, 0, 0, 0);

    float p1[4], p2[4];
#pragma unroll
    for (int r = 0; r < 4; ++r) {
      const int key1 = kt + 4 * g + r;
      const int key2 = key1 + 16;
      const bool v1 = (key1 >= 0) & (key1 < NS) &
                      (is_global | ((key1 - q <= WIN) & (q - key1 <= WIN)));
      const bool v2 = (key2 >= 0) & (key2 < NS) &
                      (is_global | ((key2 - q <= WIN) & (q - key2 <= WIN)));
      p1[r] = __expf(v1 ? st1[r] * 0.125f : -1e30f);
      p2[r] = __expf(v2 ? st2[r] * 0.125f : -1e30f);
      lacc += p1[r] + p2[r];
    }

    const int srcA = (2 * (g & 1)) * 16 + c;
    const int srcB = srcA + 16;
    short8 pf;
#pragma unroll
    for (int r = 0; r < 4; ++r) {
      const float f1a = __shfl(p1[r], srcA);
      const float f1b = __shfl(p1[r], srcB);
      const float f2a = __shfl(p2[r], srcA);
      const float f2b = __shfl(p2[r], srcB);
      pf[r]     = f2bf((g < 2) ? f1a : f2a);
      pf[4 + r] = f2bf((g < 2) ? f1b : f2b);
    }

    const int ks = min(max(kt + 8 * g, 0), NS - 8);
    const short* vrow = VT + base + (size_t)c * NS + ks;
    const short8 vf0 = *(const short8*)(vrow);
    const short8 vf1 = *(const short8*)(vrow + 16 * NS);
    const short8 vf2 = *(const short8*)(vrow + 32 * NS);
    const short8 vf3 = *(const short8*)(vrow + 48 * NS);
    O0 = __builtin_amdgcn_mfma_f32_16x16x32_bf16(vf0, pf, O0, 0, 0, 0);
    O1 = __builtin_amdgcn_mfma_f32_16x16x32_bf16(vf1, pf, O1, 0, 0, 0);
    O2 = __builtin_amdgcn_mfma_f32_16x16x32_bf16(vf2, pf, O2, 0, 0, 0);
    O3 = __builtin_amdgcn_mfma_f32_16x16x32_bf16(vf3, pf, O3, 0, 0, 0);
  }

  // publish partials: [wave][k][lane] layout -> conflict-free (lane-major)
  red[wv][16][lane] = lacc;
#pragma unroll
  for (int r = 0; r < 4; ++r) {
    red[wv][r][lane]      = O0[r];
    red[wv][4 + r][lane]  = O1[r];
    red[wv][8 + r][lane]  = O2[r];
    red[wv][12 + r][lane] = O3[r];
  }
  __syncthreads();
  if (half) return;   // no further barriers below -> early exit is safe

  // merge with partner wave (wv+4), then cross-quad reduce l and store
  const float* pr = &red[wv + 4][0][lane];
#pragma unroll
  for (int r = 0; r < 4; ++r) {
    O0[r] += pr[(r)      * 64];
    O1[r] += pr[(4 + r)  * 64];
    O2[r] += pr[(8 + r)  * 64];
    O3[r] += pr[(12 + r) * 64];
  }
  lacc += pr[16 * 64];

  lacc += __shfl_xor(lacc, 16);
  lacc += __shfl_xor(lacc, 32);
  const float inv = 1.0f / lacc;
  short* crow = CTXb + ((size_t)(b * NS + q) * NH + h) * HD;
#pragma unroll
  for (int r = 0; r < 4; ++r) {
    const int d = 4 * g + r;
    crow[d]      = f2bf(O0[r] * inv);
    crow[d + 16] = f2bf(O1[r] * inv);
    crow[d + 32] = f2bf(O2[r] * inv);
    crow[d + 48] = f2bf(O3[r] * inv);
  }
}

// ---------------------------------------------------------------------------
extern "C" void kernel_launch(void* const* d_in, const int* in_sizes, int n_in,
                              void* d_out, int out_size, void* d_ws, size_t ws_size,
                              hipStream_t stream) {
  const float* x    = (const float*)d_in[0];
  const float* Wqkv = (const float*)d_in[1];
  const float* bqkv = (const float*)d_in[2];
  const float* Wout = (const float*)d_in[3];
  const float* bout = (const float*)d_in[4];
  const int* layer_idx = (const int*)d_in[5];

  short* xb    = (short*)d_ws;                         // [4096][768]
  short* Wqkvt = xb + (size_t)NB * NS * ND;            // [2304][768]
  short* Woutt = Wqkvt + (size_t)ND * N_QKV;           // [768][768]
  short* Qb    = Woutt + (size_t)ND * ND;              // [bh][s][64]
  short* Kb    = Qb + (size_t)QKN;
  short* VT    = Kb + (size_t)QKN;                     // [bh][64][s]
  short* CTXb  = VT + (size_t)QKN;                     // [4096][768]
  // total: 18087936 shorts = 36.2 MB

  // phase 0: all preps in one dispatch
  prep_kernel<<<5376, 256, 0, stream>>>(x, Wqkv, Wout, xb, Wqkvt, Woutt);

  // QKV GEMM + RoPE: M=4096, N=2304, K=768. 32 m-tiles x 36 n-tiles = 1152.
  mfma_gemm128_kernel<0><<<1152, 256, 0, stream>>>(
      xb, Wqkvt, bqkv, layer_idx, Qb, Kb, VT, nullptr, ND, N_QKV, 36, 4);

  // split-K attention: 768 blocks x 512 threads (8 waves)
  attn_mfma_kernel<<<NB * NH * (NS / 64), 512, 0, stream>>>(Qb, Kb, VT, CTXb, layer_idx);

  // Out projection: M=4096, N=768, K=768. 32 m-tiles x 12 n-tiles = 384.
  mfma_gemm128_kernel<1><<<384, 256, 0, stream>>>(
      CTXb, Woutt, bout, layer_idx, nullptr, nullptr, nullptr, (float*)d_out, ND, ND, 12, 4);
}

// Round 10
// 141.347 us; speedup vs baseline: 1.1323x; 1.0466x over previous
//
#include <hip/hip_runtime.h>
#include <hip/hip_bf16.h>
#include <math.h>

#define NB 2
#define NS 2048
#define ND 768
#define NH 12
#define HD 64
#define WIN 128
#define N_QKV 2304
#define QKN (NB * NH * NS * HD)   // 3145728

typedef __attribute__((ext_vector_type(8))) short short8;
typedef __attribute__((ext_vector_type(4))) short short4v;
typedef __attribute__((ext_vector_type(4))) float float4v;

static __device__ __forceinline__ short f2bf(float f) {
  __hip_bfloat16 h = __float2bfloat16(f);
  short s;
  __builtin_memcpy(&s, &h, 2);
  return s;
}

static __device__ __forceinline__ void async_copy16(void* lds, const void* g) {
  __builtin_amdgcn_global_load_lds(
      (const __attribute__((address_space(1))) unsigned int*)g,
      (__attribute__((address_space(3))) unsigned int*)(unsigned int)(unsigned long long)lds,
      16, 0, 0);
}

// ---------------------------------------------------------------------------
// Merged prep kernel: x cvt (3072 units) + Wqkv^T (1728) + Wout^T (576).
// (Exact R0 form.)
// ---------------------------------------------------------------------------
__global__ __launch_bounds__(256) void prep_kernel(
    const float* __restrict__ x, const float* __restrict__ Wqkv,
    const float* __restrict__ Wout, short* __restrict__ xb,
    short* __restrict__ Wqkvt, short* __restrict__ Woutt)
{
  __shared__ float t[32][33];
  const int u = blockIdx.x;
  const int tid = threadIdx.x;

  if (u < 3072) {
    const int i = u * 1024 + tid * 4;
    const float4 v = *(const float4*)(x + i);
    short4v o;
    o[0] = f2bf(v.x); o[1] = f2bf(v.y); o[2] = f2bf(v.z); o[3] = f2bf(v.w);
    *(short4v*)(xb + i) = o;
    return;
  }

  const bool isqkv = (u < 4800);
  const float* in = isqkv ? Wqkv : Wout;
  short* out = isqkv ? Wqkvt : Woutt;
  const int C = isqkv ? N_QKV : ND;       // in cols
  const int tt = u - (isqkv ? 3072 : 4800);
  const int nbx = C / 32;
  const int bx = (tt % nbx) * 32;         // col base
  const int by = (tt / nbx) * 32;         // row base
  const int tx = tid & 31, ty = tid >> 5; // ty 0..7
#pragma unroll
  for (int i = 0; i < 32; i += 8)
    t[ty + i][tx] = in[(size_t)(by + ty + i) * C + bx + tx];
  __syncthreads();
#pragma unroll
  for (int i = 0; i < 32; i += 8)
    out[(size_t)(bx + ty + i) * ND + by + tx] = f2bf(t[tx][ty + i]);
}

// ---------------------------------------------------------------------------
// R10: QKV GEMM on a 128x128 tile with 8 WAVES (512 threads), waves 4x2.
// Each wave keeps EXACTLY R0's per-wave job (32x64 out, acc[2][4], same
// frag loads, same per-thread epilogue) -> VGPR/epilogue identical to the
// verified config. Block-level: staged bytes/output -33%, A re-read 36->18x,
// barrier pairs per output halve. Grid 576 = same 16 waves/CU residency.
// (R1's 128x128 failure used 4 fat waves — different config.)
// ---------------------------------------------------------------------------
__global__ __launch_bounds__(512) void mfma_gemm_qkv8_kernel(
    const short* __restrict__ A, const short* __restrict__ Bt,
    const float* __restrict__ bias, const int* __restrict__ layer_idx_p,
    short* __restrict__ Qb, short* __restrict__ Kb, short* __restrict__ VT,
    int K)
{
  __shared__ short As[128 * 64];   // 16 KB
  __shared__ short Bs[128 * 64];   // 16 KB
  const int tid = threadIdx.x;
  const int w = tid >> 6, lane = tid & 63;   // w 0..7
  const int c = lane & 15, g = lane >> 4;

  // XCD-aware swizzle: xcd = id&7 owns m-tiles [xcd*4, xcd*4+4)
  const int id = blockIdx.x;
  const int xcd = id & 7;
  const int k = id >> 3;               // 0..71
  const int mt = xcd * 4 + k / 18;
  const int nt = k - (k / 18) * 18;
  const int bm = mt * 128, bn = nt * 128;

  const int lr = lane >> 3;            // staging row 0..7
  const int gch = (lane & 7) ^ lr;     // swizzled global K-chunk index

  float4v acc[2][4];
#pragma unroll
  for (int i = 0; i < 2; ++i)
#pragma unroll
    for (int j = 0; j < 4; ++j) acc[i][j] = (float4v){0.f, 0.f, 0.f, 0.f};

  // staging: wave w covers rows [w*16, w*16+16) of both A and B tiles
  const short* Ag = A + (size_t)(bm + w * 16 + lr) * K + gch * 8;
  const short* Bg = Bt + (size_t)(bn + w * 16 + lr) * K + gch * 8;
  short* AsW = As + (w * 16) * 64;
  short* BsW = Bs + (w * 16) * 64;

  // compute: wave w owns out sub-tile rows (w>>1)*32, cols (w&1)*64
  const int cl7 = c & 7;
  const short* aw = As + ((w >> 1) * 32 + c) * 64;
  const short* bwp = Bs + ((w & 1) * 64 + c) * 64;

  for (int k0 = 0; k0 < K; k0 += 64) {
    async_copy16(AsW,       Ag + k0);
    async_copy16(AsW + 512, Ag + k0 + (size_t)8 * K);
    async_copy16(BsW,       Bg + k0);
    async_copy16(BsW + 512, Bg + k0 + (size_t)8 * K);
    __syncthreads();   // drains vmcnt -> staged data visible

    short8 af[2][2], bfr[4][2];
#pragma unroll
    for (int t = 0; t < 2; ++t) {
      const int slot = ((t * 4 + g) ^ cl7) * 8;
#pragma unroll
      for (int i = 0; i < 2; ++i) af[i][t] = *(const short8*)(aw + i * 16 * 64 + slot);
#pragma unroll
      for (int j = 0; j < 4; ++j) bfr[j][t] = *(const short8*)(bwp + j * 16 * 64 + slot);
    }
#pragma unroll
    for (int t = 0; t < 2; ++t)
#pragma unroll
      for (int i = 0; i < 2; ++i)
#pragma unroll
        for (int j = 0; j < 4; ++j)
          acc[i][j] = __builtin_amdgcn_mfma_f32_16x16x32_bf16(af[i][t], bfr[j][t], acc[i][j], 0, 0, 0);
    __syncthreads();   // protect LDS before next stage
  }

  const int wn = bn + (w & 1) * 64;        // wave's 64-col strip
  float bj[4];
#pragma unroll
  for (int j = 0; j < 4; ++j) bj[j] = bias[wn + j * 16 + c];

  const int which = bn / ND;               // uniform per block (768%128==0)
  const int hd0 = wn - which * ND;         // 64-aligned -> one head per wave
  const int h = hd0 >> 6;
  const int bidx = bm >> 11;
  const int srow = (bm & (NS - 1)) + (w >> 1) * 32;

  if (which == 2) {
    // V: no RoPE; VT[bh][d][s], short4 along s
#pragma unroll
    for (int j = 0; j < 4; ++j) {
      const int d = j * 16 + c;
      short* vbase = VT + ((size_t)(bidx * NH + h) * HD + d) * NS;
#pragma unroll
      for (int i = 0; i < 2; ++i) {
        short4v v4;
#pragma unroll
        for (int r = 0; r < 4; ++r) v4[r] = f2bf(acc[i][j][r] + bj[j]);
        *(short4v*)(vbase + srow + i * 16 + 4 * g) = v4;
      }
    }
  } else {
    const bool is_global = ((*layer_idx_p) % 3) == 0;
    const float theta = is_global ? 160000.0f : 10000.0f;
    const float nlt = -__logf(theta) * (1.0f / 64.0f);
    short* dst = which ? Kb : Qb;
    const bool oddc = (c & 1);
#pragma unroll
    for (int j = 0; j < 4; ++j) {
      const int d = j * 16 + c;
      const float freq = __expf((float)(d & ~1) * nlt);
#pragma unroll
      for (int i = 0; i < 2; ++i) {
#pragma unroll
        for (int r = 0; r < 4; ++r) {
          const float val = acc[i][j][r] + bj[j];
          const float partner = __shfl_xor(val, 1);
          const int s = srow + i * 16 + 4 * g + r;
          float sn, cs;
          __sincosf((float)s * freq, &sn, &cs);
          const float o = oddc ? (val * cs + partner * sn)
                               : (val * cs - partner * sn);
          dst[((size_t)(bidx * NH + h) * NS + s) * HD + d] = f2bf(o);
        }
      }
    }
  }
}

// ---------------------------------------------------------------------------
// Out projection: R0's 128x64-tile GEMM (4 waves), fp32 epilogue.
// ---------------------------------------------------------------------------
__global__ __launch_bounds__(256) void mfma_gemm_out_kernel(
    const short* __restrict__ A, const short* __restrict__ Bt,
    const float* __restrict__ bias, float* __restrict__ Out,
    int K, int Ncols, int nTN, int mPerXcd)
{
  __shared__ short As[128 * 64];   // 16 KB
  __shared__ short Bs[64 * 64];    //  8 KB
  const int tid = threadIdx.x;
  const int w = tid >> 6, lane = tid & 63;
  const int c = lane & 15, g = lane >> 4;

  const int id = blockIdx.x;
  const int xcd = id & 7;
  const int k = id >> 3;
  const int mt = xcd * mPerXcd + k / nTN;
  const int nt = k - (k / nTN) * nTN;
  const int bm = mt * 128, bn = nt * 64;

  const int lr = lane >> 3;
  const int gch = (lane & 7) ^ lr;

  float4v acc[2][4];
#pragma unroll
  for (int i = 0; i < 2; ++i)
#pragma unroll
    for (int j = 0; j < 4; ++j) acc[i][j] = (float4v){0.f, 0.f, 0.f, 0.f};

  const short* Ag = A + (size_t)(bm + w * 32 + lr) * K + gch * 8;
  const short* Bg = Bt + (size_t)(bn + w * 16 + lr) * K + gch * 8;
  short* AsW = As + (w * 32) * 64;
  short* BsW = Bs + (w * 16) * 64;

  const int cl7 = c & 7;
  const short* aw = As + (w * 32 + c) * 64;
  const short* bwp = Bs + c * 64;

  for (int k0 = 0; k0 < K; k0 += 64) {
    async_copy16(AsW,        Ag + k0);
    async_copy16(AsW + 512,  Ag + k0 + (size_t)8 * K);
    async_copy16(AsW + 1024, Ag + k0 + (size_t)16 * K);
    async_copy16(AsW + 1536, Ag + k0 + (size_t)24 * K);
    async_copy16(BsW,        Bg + k0);
    async_copy16(BsW + 512,  Bg + k0 + (size_t)8 * K);
    __syncthreads();

    short8 af[2][2], bfr[4][2];
#pragma unroll
    for (int t = 0; t < 2; ++t) {
      const int slot = ((t * 4 + g) ^ cl7) * 8;
#pragma unroll
      for (int i = 0; i < 2; ++i) af[i][t] = *(const short8*)(aw + i * 16 * 64 + slot);
#pragma unroll
      for (int j = 0; j < 4; ++j) bfr[j][t] = *(const short8*)(bwp + j * 16 * 64 + slot);
    }
#pragma unroll
    for (int t = 0; t < 2; ++t)
#pragma unroll
      for (int i = 0; i < 2; ++i)
#pragma unroll
        for (int j = 0; j < 4; ++j)
          acc[i][j] = __builtin_amdgcn_mfma_f32_16x16x32_bf16(af[i][t], bfr[j][t], acc[i][j], 0, 0, 0);
    __syncthreads();
  }

  const int wm = bm + w * 32;
  const int wn = bn;
  float bj[4];
#pragma unroll
  for (int j = 0; j < 4; ++j) bj[j] = bias[wn + j * 16 + c];

#pragma unroll
  for (int i = 0; i < 2; ++i)
#pragma unroll
    for (int j = 0; j < 4; ++j)
#pragma unroll
      for (int r = 0; r < 4; ++r)
        Out[(size_t)(wm + i * 16 + 4 * g + r) * Ncols + wn + j * 16 + c] =
            acc[i][j][r] + bj[j];
}

// ---------------------------------------------------------------------------
// MFMA banded flash attention (fixed-reference softmax). XCD-aware swizzle
// — each XCD owns 3 heads. (Exact R0 form — split-K was neutral, reverted.)
// ---------------------------------------------------------------------------
__global__ __launch_bounds__(256) void attn_mfma_kernel(
    const short* __restrict__ Qb, const short* __restrict__ Kb,
    const short* __restrict__ VT, short* __restrict__ CTXb,
    const int* __restrict__ layer_idx_p)
{
  const int lane = threadIdx.x & 63;
  const int wv = threadIdx.x >> 6;
  const int c = lane & 15;
  const int g = lane >> 4;

  // swizzle: xcd = id&7 owns bh in [xcd*3, xcd*3+3)
  const int id = blockIdx.x;
  const int xcd = id & 7;
  const int k = id >> 3;               // 0..95
  const int bh = xcd * 3 + (k >> 5);
  const int qt = k & 31;

  const int b = bh / NH;
  const int h = bh - b * NH;
  const int q0 = qt * 64 + wv * 16;
  const bool is_global = ((*layer_idx_p) % 3) == 0;
  const size_t base = (size_t)bh * NS * HD;

  const short* qrow = Qb + base + (size_t)(q0 + c) * HD + g * 8;
  const short8 qf0 = *(const short8*)(qrow);
  const short8 qf1 = *(const short8*)(qrow + 32);

  float4v O0 = {0.f, 0.f, 0.f, 0.f}, O1 = O0, O2 = O0, O3 = O0;
  float lacc = 0.0f;
  const int q = q0 + c;

  const int lo = is_global ? 0 : q0 - 128;
  const int hi = is_global ? (NS - 1) : q0 + 143;

  for (int kt = lo; kt <= hi; kt += 32) {
    if (kt + 31 < 0 || kt >= NS) continue;

    const int k1c = min(max(kt + c, 0), NS - 1);
    const int k2c = min(max(kt + 16 + c, 0), NS - 1);
    const short* kr1 = Kb + base + (size_t)k1c * HD + g * 8;
    const short* kr2 = Kb + base + (size_t)k2c * HD + g * 8;
    const short8 kf10 = *(const short8*)kr1;
    const short8 kf11 = *(const short8*)(kr1 + 32);
    const short8 kf20 = *(const short8*)kr2;
    const short8 kf21 = *(const short8*)(kr2 + 32);
    float4v st1 = {0.f, 0.f, 0.f, 0.f}, st2 = {0.f, 0.f, 0.f, 0.f};
    st1 = __builtin_amdgcn_mfma_f32_16x16x32_bf16(kf10, qf0, st1, 0, 0, 0);
    st1 = __builtin_amdgcn_mfma_f32_16x16x32_bf16(kf11, qf1, st1, 0, 0, 0);
    st2 = __builtin_amdgcn_mfma_f32_16x16x32_bf16(kf20, qf0, st2, 0, 0, 0);
    st2 = __builtin_amdgcn_mfma_f32_16x16x32_bf16(kf21, qf1, st2, 0, 0, 0);

    float p1[4], p2[4];
#pragma unroll
    for (int r = 0; r < 4; ++r) {
      const int key1 = kt + 4 * g + r;
      const int key2 = key1 + 16;
      const bool v1 = (key1 >= 0) & (key1 < NS) &
                      (is_global | ((key1 - q <= WIN) & (q - key1 <= WIN)));
      const bool v2 = (key2 >= 0) & (key2 < NS) &
                      (is_global | ((key2 - q <= WIN) & (q - key2 <= WIN)));
      p1[r] = __expf(v1 ? st1[r] * 0.125f : -1e30f);
      p2[r] = __expf(v2 ? st2[r] * 0.125f : -1e30f);
      lacc += p1[r] + p2[r];
    }

    const int srcA = (2 * (g & 1)) * 16 + c;
    const int srcB = srcA + 16;
    short8 pf;
#pragma unroll
    for (int r = 0; r < 4; ++r) {
      const float f1a = __shfl(p1[r], srcA);
      const float f1b = __shfl(p1[r], srcB);
      const float f2a = __shfl(p2[r], srcA);
      const float f2b = __shfl(p2[r], srcB);
      pf[r]     = f2bf((g < 2) ? f1a : f2a);
      pf[4 + r] = f2bf((g < 2) ? f1b : f2b);
    }

    const int ks = min(max(kt + 8 * g, 0), NS - 8);
    const short* vrow = VT + base + (size_t)c * NS + ks;
    const short8 vf0 = *(const short8*)(vrow);
    const short8 vf1 = *(const short8*)(vrow + 16 * NS);
    const short8 vf2 = *(const short8*)(vrow + 32 * NS);
    const short8 vf3 = *(const short8*)(vrow + 48 * NS);
    O0 = __builtin_amdgcn_mfma_f32_16x16x32_bf16(vf0, pf, O0, 0, 0, 0);
    O1 = __builtin_amdgcn_mfma_f32_16x16x32_bf16(vf1, pf, O1, 0, 0, 0);
    O2 = __builtin_amdgcn_mfma_f32_16x16x32_bf16(vf2, pf, O2, 0, 0, 0);
    O3 = __builtin_amdgcn_mfma_f32_16x16x32_bf16(vf3, pf, O3, 0, 0, 0);
  }

  // epilogue: one cross-quad reduction of l, then scale+store
  lacc += __shfl_xor(lacc, 16);
  lacc += __shfl_xor(lacc, 32);
  const float inv = 1.0f / lacc;
  short* crow = CTXb + ((size_t)(b * NS + q) * NH + h) * HD;
#pragma unroll
  for (int r = 0; r < 4; ++r) {
    const int d = 4 * g + r;
    crow[d]      = f2bf(O0[r] * inv);
    crow[d + 16] = f2bf(O1[r] * inv);
    crow[d + 32] = f2bf(O2[r] * inv);
    crow[d + 48] = f2bf(O3[r] * inv);
  }
}

// ---------------------------------------------------------------------------
extern "C" void kernel_launch(void* const* d_in, const int* in_sizes, int n_in,
                              void* d_out, int out_size, void* d_ws, size_t ws_size,
                              hipStream_t stream) {
  const float* x    = (const float*)d_in[0];
  const float* Wqkv = (const float*)d_in[1];
  const float* bqkv = (const float*)d_in[2];
  const float* Wout = (const float*)d_in[3];
  const float* bout = (const float*)d_in[4];
  const int* layer_idx = (const int*)d_in[5];

  short* xb    = (short*)d_ws;                         // [4096][768]
  short* Wqkvt = xb + (size_t)NB * NS * ND;            // [2304][768]
  short* Woutt = Wqkvt + (size_t)ND * N_QKV;           // [768][768]
  short* Qb    = Woutt + (size_t)ND * ND;              // [bh][s][64]
  short* Kb    = Qb + (size_t)QKN;
  short* VT    = Kb + (size_t)QKN;                     // [bh][64][s]
  short* CTXb  = VT + (size_t)QKN;                     // [4096][768]
  // total: 18087936 shorts = 36.2 MB

  // phase 0: all preps in one dispatch
  prep_kernel<<<5376, 256, 0, stream>>>(x, Wqkv, Wout, xb, Wqkvt, Woutt);

  // QKV GEMM + RoPE: M=4096, N=2304, K=768. 32 m x 18 n = 576 blocks, 8 waves.
  mfma_gemm_qkv8_kernel<<<576, 512, 0, stream>>>(
      xb, Wqkvt, bqkv, layer_idx, Qb, Kb, VT, ND);

  attn_mfma_kernel<<<NB * NH * (NS / 64), 256, 0, stream>>>(Qb, Kb, VT, CTXb, layer_idx);

  // Out projection: M=4096, N=768, K=768. 32 m-tiles x 12 n-tiles = 384.
  mfma_gemm_out_kernel<<<384, 256, 0, stream>>>(
      CTXb, Woutt, bout, (float*)d_out, ND, ND, 12, 4);
}